// Round 8
// baseline (1811.030 us; speedup 1.0000x reference)
//
#include <hip/hip_runtime.h>

#define NN 100000
#define NE 1600000
#define IN_CH 128
#define EAC 16
#define MID 128
#define OUTC 128

#define TILE 64
#define THREADS 256
#define H1STR 129    // LDS row stride (odd -> conflict-free column access)
#define EB 256       // edges per block in edge_kernel

__device__ __forceinline__ void atomic_add_f32(float* p, float v) {
    unsafeAtomicAdd(p, v);   // native global_atomic_add_f32
}

// ---------------- xw_kernel: xw = x @ W1[:128] + b1  (dense, row-local) ----------------
__global__ __launch_bounds__(THREADS, 4)
void xw_kernel(const float* __restrict__ x, const float* __restrict__ W1,
               const float* __restrict__ b1, float* __restrict__ xw)
{
    __shared__ float buf[TILE * H1STR];   // 33 KB
    const int tid = threadIdx.x;
    const long n0 = (long)blockIdx.x * TILE;
    const int nn = (int)min((long)TILE, (long)NN - n0);

    for (int i = tid; i < TILE * 32; i += THREADS) {
        int e = i >> 5, seg = i & 31;
        float4 v = make_float4(0.f, 0.f, 0.f, 0.f);
        if (e < nn) v = *(const float4*)&x[(size_t)(n0 + e) * IN_CH + seg * 4];
        int base = e * H1STR + seg * 4;
        buf[base + 0] = v.x; buf[base + 1] = v.y;
        buf[base + 2] = v.z; buf[base + 3] = v.w;
    }
    __syncthreads();

    const int lane = tid & 63;
    const int wv = __builtin_amdgcn_readfirstlane(tid >> 6);  // wave-uniform -> scalar W loads
    const int ob = wv * 32;

    float acc[32];
    const float* fl = &buf[lane * H1STR];
    #pragma unroll
    for (int u = 0; u < 32; ++u) acc[u] = b1[ob + u];
    #pragma unroll 2
    for (int k = 0; k < IN_CH; ++k) {
        float f = fl[k];
        const float* wr = &W1[(size_t)k * MID + ob];
        #pragma unroll
        for (int u = 0; u < 32; ++u) acc[u] = fmaf(f, wr[u], acc[u]);
    }
    if (lane < nn) {
        float* orow = &xw[(size_t)(n0 + lane) * MID + ob];
        #pragma unroll
        for (int u = 0; u < 32; ++u) orow[u] = acc[u];
    }
}

// ---------------- edge_kernel: h1 = ReLU(xw[col] + ea @ W1b); coalesced atomic scatter into sumh[row] ----------------
// Per-edge work is now only 16x128 FMA; one wave processes one edge (2 channels/lane).
__global__ __launch_bounds__(THREADS, 8)
void edge_kernel(const float* __restrict__ xw,
                 const int* __restrict__ eidx,      // [2, NE]: [0]=row(dst), [1]=col(src)
                 const float* __restrict__ ea,      // [NE, 16]
                 const float* __restrict__ W1b,     // = W1 + 128*128, [16][128]
                 float* __restrict__ sumh,          // = d_out, pre-zeroed
                 float* __restrict__ cnt)
{
    __shared__ float s_w[EAC][MID];    // 8 KB
    __shared__ int s_row[EB];
    __shared__ int s_col[EB];

    const int tid = threadIdx.x;
    const long e0 = (long)blockIdx.x * EB;

    // stage W1b (2048 f32 = 512 float4)
    for (int i = tid; i < 512; i += THREADS) {
        float4 v = *(const float4*)&W1b[i * 4];
        *(float4*)&((float*)s_w)[i * 4] = v;
    }
    // stage indices (NE % EB == 0, no tail)
    s_row[tid] = eidx[e0 + tid];
    s_col[tid] = eidx[NE + e0 + tid];
    __syncthreads();

    const int l  = tid & 63;
    const int wv = tid >> 6;

    #pragma unroll 2
    for (int j = 0; j < EB / 4; ++j) {
        const int e = wv * (EB / 4) + j;            // contiguous edges per wave
        const int src = s_col[e];                   // LDS broadcast
        const int dst = s_row[e];
        // ea[e][0..15]: lane l holds ea[l&15]; broadcast via shfl
        float a = ea[(size_t)(e0 + e) * EAC + (l & 15)];
        // gather xw row: 64 lanes x float2 = 512B coalesced
        float2 acc = *(const float2*)&xw[(size_t)src * MID + 2 * l];
        #pragma unroll
        for (int k = 0; k < EAC; ++k) {
            float ak = __shfl(a, k);
            float2 w = *(const float2*)&s_w[k][2 * l];
            acc.x = fmaf(ak, w.x, acc.x);
            acc.y = fmaf(ak, w.y, acc.y);
        }
        acc.x = fmaxf(acc.x, 0.f);
        acc.y = fmaxf(acc.y, 0.f);
        float* p = &sumh[(size_t)dst * MID + 2 * l];
        atomic_add_f32(p + 0, acc.x);
        atomic_add_f32(p + 1, acc.y);
        if (l == 0) atomic_add_f32(&cnt[dst], 1.0f);
    }
}

// ---------------- node_kernel (in-place on d_out): mean = (io/max(cnt,1))@W2 + (cnt>0)*b2 ; io = ReLU(mean@W3+b3)@W4+b4 ----------------
__global__ __launch_bounds__(THREADS, 4)
void node_kernel(float* __restrict__ io, const float* __restrict__ cnt,
                 const float* __restrict__ W2, const float* __restrict__ b2,
                 const float* __restrict__ W3, const float* __restrict__ b3,
                 const float* __restrict__ W4, const float* __restrict__ b4)
{
    __shared__ float buf[TILE * H1STR];   // 33 KB, reused across all 3 GEMMs
    __shared__ float s_flag[TILE];

    const int tid = threadIdx.x;
    const long n0 = (long)blockIdx.x * TILE;
    const int nn = (int)min((long)TILE, (long)NN - n0);

    if (tid < TILE) {
        float c = (tid < nn) ? cnt[n0 + tid] : 0.f;
        s_flag[tid] = (c > 0.f) ? 1.f : 0.f;
    }

    // load mean = sumh / max(cnt,1) from io
    for (int i = tid; i < TILE * 32; i += THREADS) {
        int e = i >> 5, seg = i & 31;
        float4 v = make_float4(0.f, 0.f, 0.f, 0.f);
        if (e < nn) {
            v = *(const float4*)&io[(size_t)(n0 + e) * MID + seg * 4];
            float inv = 1.0f / fmaxf(cnt[n0 + e], 1.0f);
            v.x *= inv; v.y *= inv; v.z *= inv; v.w *= inv;
        }
        int base = e * H1STR + seg * 4;
        buf[base + 0] = v.x; buf[base + 1] = v.y;
        buf[base + 2] = v.z; buf[base + 3] = v.w;
    }
    __syncthreads();

    const int lane = tid & 63;
    const int wv = __builtin_amdgcn_readfirstlane(tid >> 6);
    const int ob = wv * 32;

    float acc[32];

    // ---- GEMM A: mean@W2 + flag*b2
    {
        const float* fl = &buf[lane * H1STR];
        const float flag = s_flag[lane];
        #pragma unroll
        for (int u = 0; u < 32; ++u) acc[u] = flag * b2[ob + u];
        #pragma unroll 2
        for (int k = 0; k < MID; ++k) {
            float f = fl[k];
            const float* wr = &W2[(size_t)k * MID + ob];
            #pragma unroll
            for (int u = 0; u < 32; ++u) acc[u] = fmaf(f, wr[u], acc[u]);
        }
    }
    __syncthreads();
    {
        float* hw = &buf[lane * H1STR + ob];
        #pragma unroll
        for (int u = 0; u < 32; ++u) hw[u] = acc[u];
    }
    __syncthreads();

    // ---- GEMM B: h2 = ReLU(buf@W3 + b3)
    {
        const float* fl = &buf[lane * H1STR];
        #pragma unroll
        for (int u = 0; u < 32; ++u) acc[u] = b3[ob + u];
        #pragma unroll 2
        for (int k = 0; k < MID; ++k) {
            float f = fl[k];
            const float* wr = &W3[(size_t)k * MID + ob];
            #pragma unroll
            for (int u = 0; u < 32; ++u) acc[u] = fmaf(f, wr[u], acc[u]);
        }
        #pragma unroll
        for (int u = 0; u < 32; ++u) acc[u] = fmaxf(acc[u], 0.f);
    }
    __syncthreads();
    {
        float* hw = &buf[lane * H1STR + ob];
        #pragma unroll
        for (int u = 0; u < 32; ++u) hw[u] = acc[u];
    }
    __syncthreads();

    // ---- GEMM C: io = buf@W4 + b4 (in-place, row-local)
    {
        const float* fl = &buf[lane * H1STR];
        #pragma unroll
        for (int u = 0; u < 32; ++u) acc[u] = b4[ob + u];
        #pragma unroll 2
        for (int k = 0; k < MID; ++k) {
            float f = fl[k];
            const float* wr = &W4[(size_t)k * MID + ob];
            #pragma unroll
            for (int u = 0; u < 32; ++u) acc[u] = fmaf(f, wr[u], acc[u]);
        }
        if (lane < nn) {
            float* orow = &io[(size_t)(n0 + lane) * OUTC + ob];
            #pragma unroll
            for (int u = 0; u < 32; ++u) orow[u] = acc[u];
        }
    }
}

extern "C" void kernel_launch(void* const* d_in, const int* in_sizes, int n_in,
                              void* d_out, int out_size, void* d_ws, size_t ws_size,
                              hipStream_t stream) {
    const float* x    = (const float*)d_in[0];
    const int*   eidx = (const int*)d_in[1];
    const float* ea   = (const float*)d_in[2];
    // d_in[3] = batch (unused)
    const float* W1 = (const float*)d_in[4];
    const float* b1 = (const float*)d_in[5];
    const float* W2 = (const float*)d_in[6];
    const float* b2 = (const float*)d_in[7];
    const float* W3 = (const float*)d_in[8];
    const float* b3 = (const float*)d_in[9];
    const float* W4 = (const float*)d_in[10];
    const float* b4 = (const float*)d_in[11];
    float* out = (float*)d_out;

    float* xw  = (float*)d_ws;                         // [NN, MID] = 51.2 MB
    float* cnt = xw + (size_t)NN * MID;                // [NN]

    // sumh accumulates directly in d_out (node_kernel then transforms it in place)
    hipMemsetAsync(d_out, 0, (size_t)NN * MID * sizeof(float), stream);
    hipMemsetAsync(cnt, 0, (size_t)NN * sizeof(float), stream);

    xw_kernel<<<(NN + TILE - 1) / TILE, THREADS, 0, stream>>>(x, W1, b1, xw);

    edge_kernel<<<NE / EB, THREADS, 0, stream>>>(
        xw, eidx, ea, W1 + (size_t)IN_CH * MID, out, cnt);

    node_kernel<<<(NN + TILE - 1) / TILE, THREADS, 0, stream>>>(
        out, cnt, W2, b2, W3, b3, W4, b4);
}

// Round 9
// 1170.846 us; speedup vs baseline: 1.5468x; 1.5468x over previous
//
#include <hip/hip_runtime.h>

#define NN 100000
#define NE 1600000
#define IN_CH 128
#define EAC 16
#define MID 128
#define OUTC 128

#define TILE 64
#define THREADS 256
#define H1STR 129    // LDS row stride (odd -> conflict-free column access)
#define EB 256       // edges per block in edge_kernel

__device__ __forceinline__ void atomic_add_f32(float* p, float v) {
    unsafeAtomicAdd(p, v);   // native global_atomic_add_f32
}

// ---------------- xw_kernel: xw = x @ W1[:128] + b1  (dense, row-local) ----------------
__global__ __launch_bounds__(THREADS, 4)
void xw_kernel(const float* __restrict__ x, const float* __restrict__ W1,
               const float* __restrict__ b1, float* __restrict__ xw)
{
    __shared__ float buf[TILE * H1STR];   // 33 KB
    const int tid = threadIdx.x;
    const long n0 = (long)blockIdx.x * TILE;
    const int nn = (int)min((long)TILE, (long)NN - n0);

    for (int i = tid; i < TILE * 32; i += THREADS) {
        int e = i >> 5, seg = i & 31;
        float4 v = make_float4(0.f, 0.f, 0.f, 0.f);
        if (e < nn) v = *(const float4*)&x[(size_t)(n0 + e) * IN_CH + seg * 4];
        int base = e * H1STR + seg * 4;
        buf[base + 0] = v.x; buf[base + 1] = v.y;
        buf[base + 2] = v.z; buf[base + 3] = v.w;
    }
    __syncthreads();

    const int lane = tid & 63;
    const int wv = __builtin_amdgcn_readfirstlane(tid >> 6);  // wave-uniform -> scalar W loads
    const int ob = wv * 32;

    float acc[32];
    const float* fl = &buf[lane * H1STR];
    #pragma unroll
    for (int u = 0; u < 32; ++u) acc[u] = b1[ob + u];
    #pragma unroll 2
    for (int k = 0; k < IN_CH; ++k) {
        float f = fl[k];
        const float* wr = &W1[(size_t)k * MID + ob];
        #pragma unroll
        for (int u = 0; u < 32; ++u) acc[u] = fmaf(f, wr[u], acc[u]);
    }
    if (lane < nn) {
        float* orow = &xw[(size_t)(n0 + lane) * MID + ob];
        #pragma unroll
        for (int u = 0; u < 32; ++u) orow[u] = acc[u];
    }
}

// ---------------- edge_kernel: h1 = ReLU(xw[col] + ea @ W1b); line-once coalesced atomic scatter into sumh[row] ----------------
// lane l owns channels l and l+64: atomic instr #1 covers 64B lines of ch 0..63 once,
// instr #2 covers ch 64..127 (different lines) once -> 8 line-RMWs per edge (R7-proven pattern).
__global__ __launch_bounds__(THREADS, 8)
void edge_kernel(const float* __restrict__ xw,
                 const int* __restrict__ eidx,      // [2, NE]: [0]=row(dst), [1]=col(src)
                 const float* __restrict__ ea,      // [NE, 16]
                 const float* __restrict__ W1b,     // = W1 + 128*128, [16][128]
                 float* __restrict__ sumh,          // = d_out, pre-zeroed
                 float* __restrict__ cnt)
{
    __shared__ float s_w[EAC][MID];    // 8 KB
    __shared__ int s_row[EB];
    __shared__ int s_col[EB];

    const int tid = threadIdx.x;
    const long e0 = (long)blockIdx.x * EB;

    // stage W1b (2048 f32 = 512 float4)
    for (int i = tid; i < 512; i += THREADS) {
        float4 v = *(const float4*)&W1b[i * 4];
        *(float4*)&((float*)s_w)[i * 4] = v;
    }
    // stage indices (NE % EB == 0, no tail)
    s_row[tid] = eidx[e0 + tid];
    s_col[tid] = eidx[NE + e0 + tid];
    __syncthreads();

    const int l  = tid & 63;
    const int wv = tid >> 6;

    #pragma unroll 2
    for (int j = 0; j < EB / 4; ++j) {
        const int e = wv * (EB / 4) + j;            // contiguous edges per wave
        const int src = s_col[e];                   // LDS broadcast
        const int dst = s_row[e];
        // ea[e][0..15]: lane l holds ea[l&15]; broadcast via shfl
        float a = ea[(size_t)(e0 + e) * EAC + (l & 15)];
        // gather xw row: lane l -> channels l and l+64 (both instrs 256B coalesced)
        float acc0 = xw[(size_t)src * MID + l];
        float acc1 = xw[(size_t)src * MID + 64 + l];
        #pragma unroll
        for (int k = 0; k < EAC; ++k) {
            float ak = __shfl(a, k);
            acc0 = fmaf(ak, s_w[k][l],      acc0);
            acc1 = fmaf(ak, s_w[k][64 + l], acc1);
        }
        acc0 = fmaxf(acc0, 0.f);
        acc1 = fmaxf(acc1, 0.f);
        float* p = &sumh[(size_t)dst * MID];
        atomic_add_f32(p + l,      acc0);
        atomic_add_f32(p + 64 + l, acc1);
        if (l == 0) atomic_add_f32(&cnt[dst], 1.0f);
    }
}

// ---------------- node_kernel (in-place on d_out): mean = (io/max(cnt,1))@W2 + (cnt>0)*b2 ; io = ReLU(mean@W3+b3)@W4+b4 ----------------
__global__ __launch_bounds__(THREADS, 4)
void node_kernel(float* __restrict__ io, const float* __restrict__ cnt,
                 const float* __restrict__ W2, const float* __restrict__ b2,
                 const float* __restrict__ W3, const float* __restrict__ b3,
                 const float* __restrict__ W4, const float* __restrict__ b4)
{
    __shared__ float buf[TILE * H1STR];   // 33 KB, reused across all 3 GEMMs
    __shared__ float s_flag[TILE];

    const int tid = threadIdx.x;
    const long n0 = (long)blockIdx.x * TILE;
    const int nn = (int)min((long)TILE, (long)NN - n0);

    if (tid < TILE) {
        float c = (tid < nn) ? cnt[n0 + tid] : 0.f;
        s_flag[tid] = (c > 0.f) ? 1.f : 0.f;
    }

    // load mean = sumh / max(cnt,1) from io
    for (int i = tid; i < TILE * 32; i += THREADS) {
        int e = i >> 5, seg = i & 31;
        float4 v = make_float4(0.f, 0.f, 0.f, 0.f);
        if (e < nn) {
            v = *(const float4*)&io[(size_t)(n0 + e) * MID + seg * 4];
            float inv = 1.0f / fmaxf(cnt[n0 + e], 1.0f);
            v.x *= inv; v.y *= inv; v.z *= inv; v.w *= inv;
        }
        int base = e * H1STR + seg * 4;
        buf[base + 0] = v.x; buf[base + 1] = v.y;
        buf[base + 2] = v.z; buf[base + 3] = v.w;
    }
    __syncthreads();

    const int lane = tid & 63;
    const int wv = __builtin_amdgcn_readfirstlane(tid >> 6);
    const int ob = wv * 32;

    float acc[32];

    // ---- GEMM A: mean@W2 + flag*b2
    {
        const float* fl = &buf[lane * H1STR];
        const float flag = s_flag[lane];
        #pragma unroll
        for (int u = 0; u < 32; ++u) acc[u] = flag * b2[ob + u];
        #pragma unroll 2
        for (int k = 0; k < MID; ++k) {
            float f = fl[k];
            const float* wr = &W2[(size_t)k * MID + ob];
            #pragma unroll
            for (int u = 0; u < 32; ++u) acc[u] = fmaf(f, wr[u], acc[u]);
        }
    }
    __syncthreads();
    {
        float* hw = &buf[lane * H1STR + ob];
        #pragma unroll
        for (int u = 0; u < 32; ++u) hw[u] = acc[u];
    }
    __syncthreads();

    // ---- GEMM B: h2 = ReLU(buf@W3 + b3)
    {
        const float* fl = &buf[lane * H1STR];
        #pragma unroll
        for (int u = 0; u < 32; ++u) acc[u] = b3[ob + u];
        #pragma unroll 2
        for (int k = 0; k < MID; ++k) {
            float f = fl[k];
            const float* wr = &W3[(size_t)k * MID + ob];
            #pragma unroll
            for (int u = 0; u < 32; ++u) acc[u] = fmaf(f, wr[u], acc[u]);
        }
        #pragma unroll
        for (int u = 0; u < 32; ++u) acc[u] = fmaxf(acc[u], 0.f);
    }
    __syncthreads();
    {
        float* hw = &buf[lane * H1STR + ob];
        #pragma unroll
        for (int u = 0; u < 32; ++u) hw[u] = acc[u];
    }
    __syncthreads();

    // ---- GEMM C: io = buf@W4 + b4 (in-place, row-local)
    {
        const float* fl = &buf[lane * H1STR];
        #pragma unroll
        for (int u = 0; u < 32; ++u) acc[u] = b4[ob + u];
        #pragma unroll 2
        for (int k = 0; k < MID; ++k) {
            float f = fl[k];
            const float* wr = &W4[(size_t)k * MID + ob];
            #pragma unroll
            for (int u = 0; u < 32; ++u) acc[u] = fmaf(f, wr[u], acc[u]);
        }
        if (lane < nn) {
            float* orow = &io[(size_t)(n0 + lane) * OUTC + ob];
            #pragma unroll
            for (int u = 0; u < 32; ++u) orow[u] = acc[u];
        }
    }
}

extern "C" void kernel_launch(void* const* d_in, const int* in_sizes, int n_in,
                              void* d_out, int out_size, void* d_ws, size_t ws_size,
                              hipStream_t stream) {
    const float* x    = (const float*)d_in[0];
    const int*   eidx = (const int*)d_in[1];
    const float* ea   = (const float*)d_in[2];
    // d_in[3] = batch (unused)
    const float* W1 = (const float*)d_in[4];
    const float* b1 = (const float*)d_in[5];
    const float* W2 = (const float*)d_in[6];
    const float* b2 = (const float*)d_in[7];
    const float* W3 = (const float*)d_in[8];
    const float* b3 = (const float*)d_in[9];
    const float* W4 = (const float*)d_in[10];
    const float* b4 = (const float*)d_in[11];
    float* out = (float*)d_out;

    float* xw  = (float*)d_ws;                         // [NN, MID] = 51.2 MB
    float* cnt = xw + (size_t)NN * MID;                // [NN]

    // sumh accumulates directly in d_out (node_kernel then transforms it in place)
    hipMemsetAsync(d_out, 0, (size_t)NN * MID * sizeof(float), stream);
    hipMemsetAsync(cnt, 0, (size_t)NN * sizeof(float), stream);

    xw_kernel<<<(NN + TILE - 1) / TILE, THREADS, 0, stream>>>(x, W1, b1, xw);

    edge_kernel<<<NE / EB, THREADS, 0, stream>>>(
        xw, eidx, ea, W1 + (size_t)IN_CH * MID, out, cnt);

    node_kernel<<<(NN + TILE - 1) / TILE, THREADS, 0, stream>>>(
        out, cnt, W2, b2, W3, b3, W4, b4);
}